// Round 10
// baseline (896.380 us; speedup 1.0000x reference)
//
#include <hip/hip_runtime.h>

typedef int   v4i __attribute__((ext_vector_type(4)));
typedef float v4f __attribute__((ext_vector_type(4)));

#define TT 1024
#define DD 256
#define HH 512
#define CB 32
#define CM (CB*TT)   // 32768 rows per chunk

static __device__ __forceinline__ double shfl_xor_d(double x, int m) {
    union { double d; int u[2]; } a; a.d = x;
    a.u[0] = __shfl_xor(a.u[0], m);
    a.u[1] = __shfl_xor(a.u[1], m);
    return a.d;
}

// ---------------------------------------------------------------------------
// prep_w: split W1 [512][256] and W2 [256][512] into 5 signed-digit i8 planes.
// w = sum_j d_j * 2^(-10-7j), truncation digits, |d|<=127.
// ---------------------------------------------------------------------------
__global__ __launch_bounds__(256) void prep_w_k(const float* __restrict__ W1,
                                                const float* __restrict__ W2,
                                                signed char* __restrict__ W1p,
                                                signed char* __restrict__ W2p) {
    int i = blockIdx.x * 256 + threadIdx.x;   // 0..131071
    {
        double a = (double)W1[i];
        double inv = 1024.0, s = 1.0 / 1024.0;
#pragma unroll
        for (int p = 0; p < 5; ++p) {
            int d = (int)(a * inv);
            a -= d * s;
            W1p[(size_t)p * 131072 + i] = (signed char)d;
            inv *= 128.0; s *= (1.0 / 128.0);
        }
    }
    {
        double a = (double)W2[i];
        double inv = 1024.0, s = 1.0 / 1024.0;
#pragma unroll
        for (int p = 0; p < 5; ++p) {
            int d = (int)(a * inv);
            a -= d * s;
            W2p[(size_t)p * 131072 + i] = (signed char)d;
            inv *= 128.0; s *= (1.0 / 128.0);
        }
    }
}

// ---------------------------------------------------------------------------
// GEMM1: raw H = x @ W1^T + b1 (f64) + per-wave 16-col row partials.
// Exact Ozaki i8 with mfma_i32_16x16x64 (acc[5] = 20 regs!). 256 thr =
// 4 waves (2m x 2n), tile 32 rows x 512 cols via 16 col-phases. A: x split
// to 5 digit planes IN-KERNEL (exact f32 pow2/trunc ops), 40 KB swizzled
// LDS, staged once. B: direct global->VGPR, depth-1 ring.
// ---------------------------------------------------------------------------
__global__ __launch_bounds__(256, 2) void gemm1_i8(
    const float* __restrict__ X, const signed char* __restrict__ W1p,
    const float* __restrict__ b1, double* __restrict__ Hn,
    double* __restrict__ PS1w, double* __restrict__ PQ1w) {
    __shared__ signed char Asm[5 * 8192];           // 40 KB

    const int tid = threadIdx.x;
    const int wave = tid >> 6, lane = tid & 63;
    const int wm = wave >> 1, wn = wave & 1;
    const int lcol = lane & 15, lq = lane >> 4;     // 16x16 fragment coords
    const int m0 = blockIdx.x * 32;

    // ---- stage A: x[32][256] f32 -> 5 digit planes (exact), swizzled ----
    {
        const int r = tid >> 3, k0 = (tid & 7) * 32;
        const float* xp = X + (size_t)(m0 + r) * DD + k0;
        const int swz = (r & 15) << 4;
#pragma unroll
        for (int half = 0; half < 2; ++half) {
            float xe[16];
#pragma unroll
            for (int q = 0; q < 4; ++q)
                *(v4f*)(xe + q * 4) = *(const v4f*)(xp + half * 16 + q * 4);
            int pk[5][4];
#pragma unroll
            for (int q = 0; q < 4; ++q)
#pragma unroll
                for (int e = 0; e < 4; ++e) {
                    float a = xe[q * 4 + e];
                    float inv = 8.0f, s = 0.125f;
#pragma unroll
                    for (int p = 0; p < 5; ++p) {
                        int dg = (int)(a * inv);      // exact: pow2 scale + trunc
                        a -= (float)dg * s;           // exact cancellation
                        int byte = (dg & 255) << (8 * e);
                        if (e == 0) pk[p][q] = byte; else pk[p][q] |= byte;
                        inv *= 128.0f; s *= (1.0f / 128.0f);
                    }
                }
#pragma unroll
            for (int p = 0; p < 5; ++p)
                *(v4i*)&Asm[p * 8192 + r * 256 + ((k0 + half * 16) ^ swz)] =
                    *(const v4i*)&pk[p][0];
        }
    }

    // per-lane B pointer: column (wn*16 + lcol), k-quarter lq
    const signed char* bptr = W1p + (size_t)(wn * 16 + lcol) * 256 + lq * 16;

    v4i bf[2][5];
#pragma unroll
    for (int j = 0; j < 5; ++j)
        bf[0][j] = *(const v4i*)(bptr + (size_t)j * 131072);

    __syncthreads();   // A ready

    const double scl[5] = {0x1p-13, 0x1p-20, 0x1p-27, 0x1p-34, 0x1p-41};
    const int arow = wm * 16 + lcol;
    const int abase = arow * 256;
    const int aswz = lcol << 4;

#pragma unroll 1
    for (int ph = 0; ph < 16; ++ph) {
        v4i acc[5];
#pragma unroll
        for (int g = 0; g < 5; ++g)
#pragma unroll
            for (int r = 0; r < 4; ++r) acc[g][r] = 0;

#pragma unroll
        for (int ks = 0; ks < 4; ++ks) {
            // prefetch stage s+1 (col-phase ph or ph+1, kstep (ks+1)&3)
            if (ks != 3 || ph != 15) {
                const int s1 = ph * 4 + ks + 1;
                const size_t off = (size_t)(s1 >> 2) * 8192 + (size_t)((ks + 1) & 3) * 64;
#pragma unroll
                for (int j = 0; j < 5; ++j)
                    bf[(ks + 1) & 1][j] = *(const v4i*)(bptr + (size_t)j * 131072 + off);
            }
            v4i af[5];
#pragma unroll
            for (int i = 0; i < 5; ++i)
                af[i] = *(const v4i*)&Asm[i * 8192 + abase +
                                          ((ks * 64 + lq * 16) ^ aswz)];
#pragma unroll
            for (int j = 0; j < 5; ++j)
#pragma unroll
                for (int i = 0; i + j < 5; ++i)
                    acc[i + j] = __builtin_amdgcn_mfma_i32_16x16x64_i8(
                        af[i], bf[ks & 1][j], acc[i + j], 0, 0, 0);
        }

        // ---- retire phase: exact recombine -> f64, store, partials ----
        const int col = ph * 32 + wn * 16 + lcol;
        const double bcol = (double)b1[col];
        double vv[4], ps[4], pq[4];
#pragma unroll
        for (int r = 0; r < 4; ++r) {
            double t = 0.0;
#pragma unroll
            for (int g = 0; g < 5; ++g) t = fma((double)acc[g][r], scl[g], t);
            vv[r] = t + bcol;
            ps[r] = vv[r]; pq[r] = vv[r] * vv[r];
        }
#pragma unroll
        for (int m = 1; m < 16; m <<= 1)
#pragma unroll
            for (int r = 0; r < 4; ++r) {
                ps[r] += shfl_xor_d(ps[r], m);
                pq[r] += shfl_xor_d(pq[r], m);
            }
#pragma unroll
        for (int r = 0; r < 4; ++r)
            Hn[(size_t)(m0 + wm * 16 + lq * 4 + r) * HH + col] = vv[r];
        if (lcol == 0) {
            const size_t qb = (size_t)(ph * 2 + wn) * CM + m0 + wm * 16 + lq * 4;
#pragma unroll
            for (int r = 0; r < 4; ++r) {
                PS1w[qb + r] = ps[r];
                PQ1w[qb + r] = pq[r];
            }
        }
    }
}

// ---------------------------------------------------------------------------
// stats1_fin: per-row (mu, iv) for LN1 from the 32 16-col-slice partials.
// ---------------------------------------------------------------------------
__global__ __launch_bounds__(256) void stats1_fin(const double* __restrict__ PS1w,
                                                  const double* __restrict__ PQ1w,
                                                  double2* __restrict__ MUIV1) {
    int row = blockIdx.x * 256 + threadIdx.x;
    double S = 0.0, Q = 0.0;
#pragma unroll
    for (int q = 0; q < 32; ++q) {
        S += PS1w[(size_t)q * CM + row];
        Q += PQ1w[(size_t)q * CM + row];
    }
    double mu = S * (1.0 / 512.0);
    double var = Q * (1.0 / 512.0) - mu * mu;
    MUIV1[row] = make_double2(mu, 1.0 / sqrt(var + 1e-5));
}

// ---------------------------------------------------------------------------
// LIF1: apply LN1 (mu,iv ring in LDS) + fp64 LIF recurrence -> spikes.
// ---------------------------------------------------------------------------
__global__ __launch_bounds__(64) void lif1_k(const double* __restrict__ Hn,
                                             const double2* __restrict__ MUIV,
                                             const float* __restrict__ g1,
                                             const float* __restrict__ be1,
                                             signed char* __restrict__ S) {
    const int b = blockIdx.x >> 3;
    const int h = (blockIdx.x & 7) * 64 + threadIdx.x;
    __shared__ double2 MI[4][16];
    const double* src = Hn + (size_t)b * TT * HH + h;
    signed char* dst = S + (size_t)b * TT * HH + h;
    const double gg = (double)g1[h], be = (double)be1[h];
    if (threadIdx.x < 48)
        MI[threadIdx.x >> 4][threadIdx.x & 15] = MUIV[(size_t)b * TT + threadIdx.x];
    double buf[4][16];
#pragma unroll
    for (int gq = 0; gq < 3; ++gq)
#pragma unroll
        for (int t = 0; t < 16; ++t)
            buf[gq][t] = src[(size_t)(gq * 16 + t) * HH];
    __syncthreads();
    double v = 0.0;
    for (int g4 = 0; g4 < 64; g4 += 4) {
#pragma unroll
        for (int u = 0; u < 4; ++u) {
            const int g = g4 + u;
            __syncthreads();
            if (g + 3 < 64) {
                if (threadIdx.x < 16)
                    MI[(g + 3) & 3][threadIdx.x] =
                        MUIV[(size_t)b * TT + (g + 3) * 16 + threadIdx.x];
#pragma unroll
                for (int t = 0; t < 16; ++t)
                    buf[(u + 3) & 3][t] = src[(size_t)((g + 3) * 16 + t) * HH];
            }
#pragma unroll
            for (int t = 0; t < 16; ++t) {
                const double2 mi = MI[g & 3][t];
                const double x = (buf[u][t] - mi.x) * mi.y * gg + be;
                v += (x - v) * 0.5;
                const bool sp = (v >= 1.0);
                dst[(size_t)(g * 16 + t) * HH] = sp ? 1 : 0;
                if (sp) v = 0.0;
            }
        }
    }
}

// ---------------------------------------------------------------------------
// GEMM2: raw Y = S @ W2^T + b2 (f64) + per-wave 16-col row partials.
// mfma 16x16x64, 256 thr = 4 waves (2m x 2n), tile 32 rows x 256 cols via
// 8 col-phases, K=512 (8 ksteps/phase). A = spikes, 16 KB swizzled LDS.
// ---------------------------------------------------------------------------
__global__ __launch_bounds__(256, 2) void gemm2_i8(
    const signed char* __restrict__ Sb, const signed char* __restrict__ W2p,
    const float* __restrict__ b2, double* __restrict__ Yn,
    double* __restrict__ PS2w, double* __restrict__ PQ2w) {
    __shared__ signed char Asm[32 * 512];           // 16 KB

    const int tid = threadIdx.x;
    const int wave = tid >> 6, lane = tid & 63;
    const int wm = wave >> 1, wn = wave & 1;
    const int lcol = lane & 15, lq = lane >> 4;
    const int m0 = blockIdx.x * 32;

    // ---- stage A (spikes [32][512], swizzled) ----
    {
        const int r = tid >> 3, k0 = (tid & 7) * 64;
        const signed char* sp = Sb + (size_t)(m0 + r) * HH + k0;
        const int swz = (r & 15) << 4;
#pragma unroll
        for (int q = 0; q < 4; ++q) {
            v4i v = *(const v4i*)(sp + q * 16);
            *(v4i*)&Asm[r * 512 + ((k0 + q * 16) ^ swz)] = v;
        }
    }

    const signed char* bptr = W2p + (size_t)(wn * 16 + lcol) * 512 + lq * 16;

    v4i bf[2][5];
#pragma unroll
    for (int j = 0; j < 5; ++j)
        bf[0][j] = *(const v4i*)(bptr + (size_t)j * 131072);

    __syncthreads();

    const double scl[5] = {0x1p-10, 0x1p-17, 0x1p-24, 0x1p-31, 0x1p-38};
    const int arow = wm * 16 + lcol;
    const int abase = arow * 512;
    const int aswz = lcol << 4;

#pragma unroll 1
    for (int ph = 0; ph < 8; ++ph) {
        v4i acc[5];
#pragma unroll
        for (int g = 0; g < 5; ++g)
#pragma unroll
            for (int r = 0; r < 4; ++r) acc[g][r] = 0;

#pragma unroll
        for (int ks = 0; ks < 8; ++ks) {
            if (ks != 7 || ph != 7) {
                const int s1 = ph * 8 + ks + 1;
                const size_t off = (size_t)(s1 >> 3) * 16384 + (size_t)((ks + 1) & 7) * 64;
#pragma unroll
                for (int j = 0; j < 5; ++j)
                    bf[(ks + 1) & 1][j] = *(const v4i*)(bptr + (size_t)j * 131072 + off);
            }
            v4i a = *(const v4i*)&Asm[abase + ((ks * 64 + lq * 16) ^ aswz)];
#pragma unroll
            for (int j = 0; j < 5; ++j)
                acc[j] = __builtin_amdgcn_mfma_i32_16x16x64_i8(
                    a, bf[ks & 1][j], acc[j], 0, 0, 0);
        }

        // ---- retire phase ----
        const int col = ph * 32 + wn * 16 + lcol;
        const double bcol = (double)b2[col];
        double vv[4], ps[4], pq[4];
#pragma unroll
        for (int r = 0; r < 4; ++r) {
            double t = 0.0;
#pragma unroll
            for (int g = 0; g < 5; ++g) t = fma((double)acc[g][r], scl[g], t);
            vv[r] = t + bcol;
            ps[r] = vv[r]; pq[r] = vv[r] * vv[r];
        }
#pragma unroll
        for (int m = 1; m < 16; m <<= 1)
#pragma unroll
            for (int r = 0; r < 4; ++r) {
                ps[r] += shfl_xor_d(ps[r], m);
                pq[r] += shfl_xor_d(pq[r], m);
            }
#pragma unroll
        for (int r = 0; r < 4; ++r)
            Yn[(size_t)(m0 + wm * 16 + lq * 4 + r) * DD + col] = vv[r];
        if (lcol == 0) {
            const size_t qb = (size_t)(ph * 2 + wn) * CM + m0 + wm * 16 + lq * 4;
#pragma unroll
            for (int r = 0; r < 4; ++r) {
                PS2w[qb + r] = ps[r];
                PQ2w[qb + r] = pq[r];
            }
        }
    }
}

// ---------------------------------------------------------------------------
// stats2_fin: per-row (mu, iv) for LN2 from the 16 16-col-slice partials.
// ---------------------------------------------------------------------------
__global__ __launch_bounds__(256) void stats2_fin(const double* __restrict__ PS2w,
                                                  const double* __restrict__ PQ2w,
                                                  double2* __restrict__ MUIV2) {
    int row = blockIdx.x * 256 + threadIdx.x;
    double S = 0.0, Q = 0.0;
#pragma unroll
    for (int q = 0; q < 16; ++q) {
        S += PS2w[(size_t)q * CM + row];
        Q += PQ2w[(size_t)q * CM + row];
    }
    double mu = S * (1.0 / 256.0);
    double var = Q * (1.0 / 256.0) - mu * mu;
    MUIV2[row] = make_double2(mu, 1.0 / sqrt(var + 1e-5));
}

// ---------------------------------------------------------------------------
// LIF2: apply LN2 + fp64 LIF + residual. out = x + spike.
// ---------------------------------------------------------------------------
__global__ __launch_bounds__(64) void lif2_k(const double* __restrict__ Yn,
                                             const double2* __restrict__ MUIV,
                                             const float* __restrict__ g2,
                                             const float* __restrict__ be2,
                                             const float* __restrict__ X,
                                             float* __restrict__ out) {
    const int b = blockIdx.x >> 2;
    const int d = (blockIdx.x & 3) * 64 + threadIdx.x;
    __shared__ double2 MI[4][16];
    const double* src = Yn + (size_t)b * TT * DD + d;
    const float* xs = X + (size_t)b * TT * DD + d;
    float* dst = out + (size_t)b * TT * DD + d;
    const double gg = (double)g2[d], be = (double)be2[d];
    if (threadIdx.x < 48)
        MI[threadIdx.x >> 4][threadIdx.x & 15] = MUIV[(size_t)b * TT + threadIdx.x];
    double bufy[4][16];
    float bufx[4][16];
#pragma unroll
    for (int gq = 0; gq < 3; ++gq)
#pragma unroll
        for (int t = 0; t < 16; ++t) {
            bufy[gq][t] = src[(size_t)(gq * 16 + t) * DD];
            bufx[gq][t] = xs[(size_t)(gq * 16 + t) * DD];
        }
    __syncthreads();
    double v = 0.0;
    for (int g4 = 0; g4 < 64; g4 += 4) {
#pragma unroll
        for (int u = 0; u < 4; ++u) {
            const int g = g4 + u;
            __syncthreads();
            if (g + 3 < 64) {
                if (threadIdx.x < 16)
                    MI[(g + 3) & 3][threadIdx.x] =
                        MUIV[(size_t)b * TT + (g + 3) * 16 + threadIdx.x];
#pragma unroll
                for (int t = 0; t < 16; ++t) {
                    bufy[(u + 3) & 3][t] = src[(size_t)((g + 3) * 16 + t) * DD];
                    bufx[(u + 3) & 3][t] = xs[(size_t)((g + 3) * 16 + t) * DD];
                }
            }
#pragma unroll
            for (int t = 0; t < 16; ++t) {
                const double2 mi = MI[g & 3][t];
                const double x = (bufy[u][t] - mi.x) * mi.y * gg + be;
                v += (x - v) * 0.5;
                const bool sp = (v >= 1.0);
                __builtin_nontemporal_store(bufx[u][t] + (sp ? 1.0f : 0.0f),
                                            &dst[(size_t)(g * 16 + t) * DD]);
                if (sp) v = 0.0;
            }
        }
    }
}

extern "C" void kernel_launch(void* const* d_in, const int* in_sizes, int n_in,
                              void* d_out, int out_size, void* d_ws, size_t ws_size,
                              hipStream_t stream) {
    const float* x   = (const float*)d_in[0];
    const float* W1  = (const float*)d_in[1];
    const float* b1  = (const float*)d_in[2];
    const float* g1  = (const float*)d_in[3];
    const float* be1 = (const float*)d_in[4];
    const float* W2  = (const float*)d_in[5];
    const float* b2  = (const float*)d_in[6];
    const float* g2  = (const float*)d_in[7];
    const float* be2 = (const float*)d_in[8];
    float* out = (float*)d_out;

    char* ws = (char*)d_ws;
    signed char* W1p = (signed char*)ws;                          // 640 KB
    signed char* W2p = (signed char*)(ws + (1ull << 20));         // 640 KB
    double*      Hn  = (double*)(ws + (2ull << 20));              // 128 MB -> 130M
    signed char* Sb  = (signed char*)(ws + (130ull << 20));       // 16 MB -> 146M
    double*      Yn  = (double*)(ws + (146ull << 20));            // 64 MB -> 210M
    // aliases in Yn region (dead before gemm2 writes Yn):
    double*      PS1w  = (double*)(ws + (146ull << 20));          // 8 MB
    double*      PQ1w  = (double*)(ws + (154ull << 20));          // 8 MB
    double2*     MUIV1 = (double2*)(ws + (162ull << 20));         // 512 KB
    // aliases in Hn region (dead after lif1):
    double*      PS2w  = (double*)(ws + (2ull << 20));            // 4 MB
    double*      PQ2w  = (double*)(ws + (6ull << 20));            // 4 MB
    double2*     MUIV2 = (double2*)(ws + (10ull << 20));          // 512 KB
    // total 210 MB

    prep_w_k<<<dim3(512), dim3(256), 0, stream>>>(W1, W2, W1p, W2p);

    for (int c = 0; c < 2; ++c) {
        const float* xc = x + (size_t)c * CM * DD;
        float* outc = out + (size_t)c * CM * DD;
        gemm1_i8<<<dim3(CM / 32), dim3(256), 0, stream>>>(xc, W1p, b1, Hn, PS1w, PQ1w);
        stats1_fin<<<dim3(CM / 256), dim3(256), 0, stream>>>(PS1w, PQ1w, MUIV1);
        lif1_k<<<dim3(CB * 8), dim3(64), 0, stream>>>(Hn, MUIV1, g1, be1, Sb);
        gemm2_i8<<<dim3(CM / 32), dim3(256), 0, stream>>>(Sb, W2p, b2, Yn, PS2w, PQ2w);
        stats2_fin<<<dim3(CM / 256), dim3(256), 0, stream>>>(PS2w, PQ2w, MUIV2);
        lif2_k<<<dim3(CB * 4), dim3(64), 0, stream>>>(Yn, MUIV2, g2, be2, xc, outc);
    }
}

// Round 11
// 702.916 us; speedup vs baseline: 1.2752x; 1.2752x over previous
//
#include <hip/hip_runtime.h>

typedef int   v4i __attribute__((ext_vector_type(4)));
typedef int  v16i __attribute__((ext_vector_type(16)));
typedef float v4f __attribute__((ext_vector_type(4)));

#define TT 1024
#define DD 256
#define HH 512
#define CB 32
#define CM (CB*TT)   // 32768 rows per chunk

static __device__ __forceinline__ double shfl_xor_d(double x, int m) {
    union { double d; int u[2]; } a; a.d = x;
    a.u[0] = __shfl_xor(a.u[0], m);
    a.u[1] = __shfl_xor(a.u[1], m);
    return a.d;
}

// ---------------------------------------------------------------------------
// prep_w: split W1 [512][256] and W2 [256][512] into 5 signed-digit i8 planes.
// ---------------------------------------------------------------------------
__global__ __launch_bounds__(256) void prep_w_k(const float* __restrict__ W1,
                                                const float* __restrict__ W2,
                                                signed char* __restrict__ W1p,
                                                signed char* __restrict__ W2p) {
    int i = blockIdx.x * 256 + threadIdx.x;   // 0..131071
    {
        double a = (double)W1[i];
        double inv = 1024.0, s = 1.0 / 1024.0;
#pragma unroll
        for (int p = 0; p < 5; ++p) {
            int d = (int)(a * inv);
            a -= d * s;
            W1p[(size_t)p * 131072 + i] = (signed char)d;
            inv *= 128.0; s *= (1.0 / 128.0);
        }
    }
    {
        double a = (double)W2[i];
        double inv = 1024.0, s = 1.0 / 1024.0;
#pragma unroll
        for (int p = 0; p < 5; ++p) {
            int d = (int)(a * inv);
            a -= d * s;
            W2p[(size_t)p * 131072 + i] = (signed char)d;
            inv *= 128.0; s *= (1.0 / 128.0);
        }
    }
}

// ---------------------------------------------------------------------------
// split_x: x chunk [CM][256] f32 -> 5 digit planes i8 (exact pow2/trunc ops).
// ---------------------------------------------------------------------------
__global__ __launch_bounds__(256) void split_x_k(const float* __restrict__ xc,
                                                 signed char* __restrict__ Xp) {
    int gid = blockIdx.x * 256 + threadIdx.x;   // 0 .. CM*64-1
    int e0 = gid * 4;
    v4f xv = *(const v4f*)(xc + e0);
    int dg[4][5];
#pragma unroll
    for (int e = 0; e < 4; ++e) {
        float a = xv[e];
        float inv = 8.0f, s = 0.125f;
#pragma unroll
        for (int p = 0; p < 5; ++p) {
            int d = (int)(a * inv);
            a -= (float)d * s;
            dg[e][p] = d;
            inv *= 128.0f; s *= (1.0f / 128.0f);
        }
    }
#pragma unroll
    for (int p = 0; p < 5; ++p) {
        int pk = (dg[0][p] & 255) | ((dg[1][p] & 255) << 8) |
                 ((dg[2][p] & 255) << 16) | ((dg[3][p] & 255) << 24);
        *(int*)(Xp + (size_t)p * ((size_t)CM * 256) + e0) = pk;
    }
}

// ---------------------------------------------------------------------------
// GEMM1: raw H = x @ W1^T + b1 (f64) + per-wave row partials (sum,sumsq).
// 256 thr = 4 waves (1m x 4n), tile 32 rows x 256 cols (grid x2 col-halves),
// 2 col-phases. A: 5 planes, 40 KB swizzled LDS. B: direct global->VGPR,
// depth-1 double-buffer bf[2][5] (saves 20 VGPR vs ring-3 -> 3 waves/SIMD).
// ---------------------------------------------------------------------------
__global__ __launch_bounds__(256, 3) void gemm1_i8(
    const signed char* __restrict__ Xp, const signed char* __restrict__ W1p,
    const float* __restrict__ b1, double* __restrict__ Hn,
    double* __restrict__ PS1w, double* __restrict__ PQ1w) {
    __shared__ signed char Asm[5 * 8192];           // 40 KB

    const int tid = threadIdx.x;
    const int wn = tid >> 6, lane = tid & 63, lrow = lane & 31, lhalf = lane >> 5;
    const int ch = blockIdx.x;           // column half of H (0/1)
    const int m0 = blockIdx.y * 32;

    // ---- stage A: 5 planes x [32][256] from Xp, swizzled ----
    {
        const int r = tid >> 3, k0 = (tid & 7) * 32;
        const int swz = (r & 15) << 4;
#pragma unroll
        for (int p = 0; p < 5; ++p) {
            const signed char* sp = Xp + (size_t)p * ((size_t)CM * 256) +
                                    (size_t)(m0 + r) * 256 + k0;
            v4i v0 = *(const v4i*)(sp);
            v4i v1 = *(const v4i*)(sp + 16);
            *(v4i*)&Asm[p * 8192 + r * 256 + (k0 ^ swz)] = v0;
            *(v4i*)&Asm[p * 8192 + r * 256 + ((k0 + 16) ^ swz)] = v1;
        }
    }

    const int colbase = ch * 256 + wn * 32 + lrow;
    const signed char* bptr = W1p + (size_t)colbase * 256 + lhalf * 16;
    // stage s = p*8 + ksl: B offset = (s>>3)*32768 + (s&7)*32 + j*131072

    v4i bf[2][5];
#pragma unroll
    for (int j = 0; j < 5; ++j)
        bf[0][j] = *(const v4i*)(bptr + (size_t)j * 131072);

    v16i acc[5];

    __syncthreads();   // A ready

    const double scl[5] = {0x1p-13, 0x1p-20, 0x1p-27, 0x1p-34, 0x1p-41};
    const int aswz = (lrow & 15) << 4;

#pragma unroll
    for (int p = 0; p < 2; ++p) {
#pragma unroll
        for (int g = 0; g < 5; ++g)
#pragma unroll
            for (int r = 0; r < 16; ++r) acc[g][r] = 0;
#pragma unroll
        for (int ksl = 0; ksl < 8; ++ksl) {
            const int s = p * 8 + ksl;
            if (s + 1 < 16) {
                const int s1 = s + 1;
#pragma unroll
                for (int j = 0; j < 5; ++j)
                    bf[s1 & 1][j] = *(const v4i*)(bptr + (size_t)j * 131072 +
                                                  (s1 >> 3) * 32768 + (s1 & 7) * 32);
            }
            v4i af[5];
#pragma unroll
            for (int i = 0; i < 5; ++i)
                af[i] = *(const v4i*)&Asm[i * 8192 + lrow * 256 +
                                          ((ksl * 32 + lhalf * 16) ^ aswz)];
#pragma unroll
            for (int j = 0; j < 5; ++j)
#pragma unroll
                for (int i = 0; i + j < 5; ++i)
                    acc[i + j] = __builtin_amdgcn_mfma_i32_32x32x32_i8(
                        af[i], bf[s & 1][j], acc[i + j], 0, 0, 0);
        }
        // ---- retire phase p: exact recombine, store, per-wave partials ----
        const int col = colbase + p * 128;
        const double bcol = (double)b1[col];
        const size_t qbase = (size_t)((ch * 2 + p) * 4 + wn) * CM + m0;
#pragma unroll
        for (int r = 0; r < 16; ++r) {
            double t = 0.0;
#pragma unroll
            for (int g = 0; g < 5; ++g) t = fma((double)acc[g][r], scl[g], t);
            const double hr = t + bcol;
            const int crow = (r & 3) + 8 * (r >> 2) + 4 * lhalf;
            Hn[(size_t)(m0 + crow) * HH + col] = hr;
            double ps = hr, pq = hr * hr;
#pragma unroll
            for (int m = 1; m < 32; m <<= 1) {
                ps += shfl_xor_d(ps, m);
                pq += shfl_xor_d(pq, m);
            }
            if (lrow == 0) {
                PS1w[qbase + crow] = ps;
                PQ1w[qbase + crow] = pq;
            }
        }
    }
}

// ---------------------------------------------------------------------------
// stats1_fin: per-row (mu, iv) for LN1 from the 16 per-wave partials.
// ---------------------------------------------------------------------------
__global__ __launch_bounds__(256) void stats1_fin(const double* __restrict__ PS1w,
                                                  const double* __restrict__ PQ1w,
                                                  double2* __restrict__ MUIV1) {
    int row = blockIdx.x * 256 + threadIdx.x;
    double S = 0.0, Q = 0.0;
#pragma unroll
    for (int q = 0; q < 16; ++q) {
        S += PS1w[(size_t)q * CM + row];
        Q += PQ1w[(size_t)q * CM + row];
    }
    double mu = S * (1.0 / 512.0);
    double var = Q * (1.0 / 512.0) - mu * mu;
    MUIV1[row] = make_double2(mu, 1.0 / sqrt(var + 1e-5));
}

// ---------------------------------------------------------------------------
// LIF1: apply LN1 (mu,iv ring in LDS) + fp64 LIF recurrence -> spikes.
// ---------------------------------------------------------------------------
__global__ __launch_bounds__(64) void lif1_k(const double* __restrict__ Hn,
                                             const double2* __restrict__ MUIV,
                                             const float* __restrict__ g1,
                                             const float* __restrict__ be1,
                                             signed char* __restrict__ S) {
    const int b = blockIdx.x >> 3;
    const int h = (blockIdx.x & 7) * 64 + threadIdx.x;
    __shared__ double2 MI[4][16];
    const double* src = Hn + (size_t)b * TT * HH + h;
    signed char* dst = S + (size_t)b * TT * HH + h;
    const double gg = (double)g1[h], be = (double)be1[h];
    if (threadIdx.x < 48)
        MI[threadIdx.x >> 4][threadIdx.x & 15] = MUIV[(size_t)b * TT + threadIdx.x];
    double buf[4][16];
#pragma unroll
    for (int gq = 0; gq < 3; ++gq)
#pragma unroll
        for (int t = 0; t < 16; ++t)
            buf[gq][t] = src[(size_t)(gq * 16 + t) * HH];
    __syncthreads();
    double v = 0.0;
    for (int g4 = 0; g4 < 64; g4 += 4) {
#pragma unroll
        for (int u = 0; u < 4; ++u) {
            const int g = g4 + u;
            __syncthreads();
            if (g + 3 < 64) {
                if (threadIdx.x < 16)
                    MI[(g + 3) & 3][threadIdx.x] =
                        MUIV[(size_t)b * TT + (g + 3) * 16 + threadIdx.x];
#pragma unroll
                for (int t = 0; t < 16; ++t)
                    buf[(u + 3) & 3][t] = src[(size_t)((g + 3) * 16 + t) * HH];
            }
#pragma unroll
            for (int t = 0; t < 16; ++t) {
                const double2 mi = MI[g & 3][t];
                const double x = (buf[u][t] - mi.x) * mi.y * gg + be;
                v += (x - v) * 0.5;
                const bool sp = (v >= 1.0);
                dst[(size_t)(g * 16 + t) * HH] = sp ? 1 : 0;
                if (sp) v = 0.0;
            }
        }
    }
}

// ---------------------------------------------------------------------------
// GEMM2: raw Y = S @ W2^T + b2 (f64) + in-block (mu,iv) for LN2.
// 256 thr = 4 waves (1m x 4n), tile 32 rows x 256 cols (full rows), 2
// col-phases. A = spikes 16 KB swizzled LDS. B: depth-1 double-buffer.
// ---------------------------------------------------------------------------
__global__ __launch_bounds__(256, 3) void gemm2_i8(
    const signed char* __restrict__ Sb, const signed char* __restrict__ W2p,
    const float* __restrict__ b2, double* __restrict__ Yn,
    double2* __restrict__ MUIV2) {
    __shared__ signed char Asm[32 * 512];         // 16 KB
    __shared__ double RSs[2][4][32], RQs[2][4][32];

    const int tid = threadIdx.x;
    const int wn = tid >> 6, lane = tid & 63, lrow = lane & 31, lhalf = lane >> 5;
    const int m0 = blockIdx.x * 32;

    // ---- stage A (spikes [32][512]) ----
    {
        const int r = tid >> 3, k0 = (tid & 7) * 64;
        const signed char* sp = Sb + (size_t)(m0 + r) * HH + k0;
        const int swz = (r & 15) << 4;
#pragma unroll
        for (int q = 0; q < 4; ++q) {
            v4i v = *(const v4i*)(sp + q * 16);
            *(v4i*)&Asm[r * 512 + ((k0 + q * 16) ^ swz)] = v;
        }
    }

    const signed char* bptr = W2p + (size_t)(wn * 32 + lrow) * 512 + lhalf * 16;
    // stage s = p*16 + ksl: B offset = (s>>4)*65536 + (s&15)*32 + j*131072

    v4i bf[2][5];
#pragma unroll
    for (int j = 0; j < 5; ++j)
        bf[0][j] = *(const v4i*)(bptr + (size_t)j * 131072);

    v16i acc[5];

    __syncthreads();

    const double scl[5] = {0x1p-10, 0x1p-17, 0x1p-24, 0x1p-31, 0x1p-38};
    const int aswz = (lrow & 15) << 4;

#pragma unroll
    for (int p = 0; p < 2; ++p) {
#pragma unroll
        for (int g = 0; g < 5; ++g)
#pragma unroll
            for (int r = 0; r < 16; ++r) acc[g][r] = 0;
#pragma unroll
        for (int ksl = 0; ksl < 16; ++ksl) {
            const int s = p * 16 + ksl;
            if (s + 1 < 32) {
                const int s1 = s + 1;
#pragma unroll
                for (int j = 0; j < 5; ++j)
                    bf[s1 & 1][j] = *(const v4i*)(bptr + (size_t)j * 131072 +
                                                  (s1 >> 4) * 65536 + (s1 & 15) * 32);
            }
            v4i a = *(const v4i*)&Asm[lrow * 512 + ((ksl * 32 + lhalf * 16) ^ aswz)];
#pragma unroll
            for (int j = 0; j < 5; ++j)
                acc[j] = __builtin_amdgcn_mfma_i32_32x32x32_i8(a, bf[s & 1][j], acc[j], 0, 0, 0);
        }
        // ---- retire phase p ----
        const int col = p * 128 + wn * 32 + lrow;
        const double bcol = (double)b2[col];
#pragma unroll
        for (int r = 0; r < 16; ++r) {
            double t = 0.0;
#pragma unroll
            for (int g = 0; g < 5; ++g) t = fma((double)acc[g][r], scl[g], t);
            const double yr = t + bcol;
            const int crow = (r & 3) + 8 * (r >> 2) + 4 * lhalf;
            Yn[(size_t)(m0 + crow) * DD + col] = yr;
            double ps = yr, pq = yr * yr;
#pragma unroll
            for (int m = 1; m < 32; m <<= 1) {
                ps += shfl_xor_d(ps, m);
                pq += shfl_xor_d(pq, m);
            }
            if (lrow == 0) {
                RSs[p][wn][crow] = ps;
                RQs[p][wn][crow] = pq;
            }
        }
    }
    __syncthreads();
    if (tid < 32) {
        double Ssum = 0.0, Qsum = 0.0;
#pragma unroll
        for (int p = 0; p < 2; ++p)
#pragma unroll
            for (int w = 0; w < 4; ++w) { Ssum += RSs[p][w][tid]; Qsum += RQs[p][w][tid]; }
        const double mu = Ssum * (1.0 / 256.0);
        const double var = Qsum * (1.0 / 256.0) - mu * mu;
        MUIV2[m0 + tid] = make_double2(mu, 1.0 / sqrt(var + 1e-5));
    }
}

// ---------------------------------------------------------------------------
// LIF2: apply LN2 + fp64 LIF + residual. out = x + spike.
// ---------------------------------------------------------------------------
__global__ __launch_bounds__(64) void lif2_k(const double* __restrict__ Yn,
                                             const double2* __restrict__ MUIV,
                                             const float* __restrict__ g2,
                                             const float* __restrict__ be2,
                                             const float* __restrict__ X,
                                             float* __restrict__ out) {
    const int b = blockIdx.x >> 2;
    const int d = (blockIdx.x & 3) * 64 + threadIdx.x;
    __shared__ double2 MI[4][16];
    const double* src = Yn + (size_t)b * TT * DD + d;
    const float* xs = X + (size_t)b * TT * DD + d;
    float* dst = out + (size_t)b * TT * DD + d;
    const double gg = (double)g2[d], be = (double)be2[d];
    if (threadIdx.x < 48)
        MI[threadIdx.x >> 4][threadIdx.x & 15] = MUIV[(size_t)b * TT + threadIdx.x];
    double bufy[4][16];
    float bufx[4][16];
#pragma unroll
    for (int gq = 0; gq < 3; ++gq)
#pragma unroll
        for (int t = 0; t < 16; ++t) {
            bufy[gq][t] = src[(size_t)(gq * 16 + t) * DD];
            bufx[gq][t] = xs[(size_t)(gq * 16 + t) * DD];
        }
    __syncthreads();
    double v = 0.0;
    for (int g4 = 0; g4 < 64; g4 += 4) {
#pragma unroll
        for (int u = 0; u < 4; ++u) {
            const int g = g4 + u;
            __syncthreads();
            if (g + 3 < 64) {
                if (threadIdx.x < 16)
                    MI[(g + 3) & 3][threadIdx.x] =
                        MUIV[(size_t)b * TT + (g + 3) * 16 + threadIdx.x];
#pragma unroll
                for (int t = 0; t < 16; ++t) {
                    bufy[(u + 3) & 3][t] = src[(size_t)((g + 3) * 16 + t) * DD];
                    bufx[(u + 3) & 3][t] = xs[(size_t)((g + 3) * 16 + t) * DD];
                }
            }
#pragma unroll
            for (int t = 0; t < 16; ++t) {
                const double2 mi = MI[g & 3][t];
                const double x = (bufy[u][t] - mi.x) * mi.y * gg + be;
                v += (x - v) * 0.5;
                const bool sp = (v >= 1.0);
                __builtin_nontemporal_store(bufx[u][t] + (sp ? 1.0f : 0.0f),
                                            &dst[(size_t)(g * 16 + t) * DD]);
                if (sp) v = 0.0;
            }
        }
    }
}

extern "C" void kernel_launch(void* const* d_in, const int* in_sizes, int n_in,
                              void* d_out, int out_size, void* d_ws, size_t ws_size,
                              hipStream_t stream) {
    const float* x   = (const float*)d_in[0];
    const float* W1  = (const float*)d_in[1];
    const float* b1  = (const float*)d_in[2];
    const float* g1  = (const float*)d_in[3];
    const float* be1 = (const float*)d_in[4];
    const float* W2  = (const float*)d_in[5];
    const float* b2  = (const float*)d_in[6];
    const float* g2  = (const float*)d_in[7];
    const float* be2 = (const float*)d_in[8];
    float* out = (float*)d_out;

    char* ws = (char*)d_ws;
    signed char* W1p = (signed char*)ws;                          // 640 KB
    signed char* W2p = (signed char*)(ws + (1ull << 20));         // 640 KB
    double*      Hn  = (double*)(ws + (2ull << 20));              // 128 MB -> 130
    signed char* Sb  = (signed char*)(ws + (130ull << 20));       // 16 MB  -> 146
    double*      Yn  = (double*)(ws + (146ull << 20));            // 64 MB  -> 210
    // transient aliases inside the Yn region (dead before gemm2 writes Yn):
    signed char* Xp    = (signed char*)(ws + (146ull << 20));     // 40 MB
    double*      PS1w  = (double*)(ws + (186ull << 20));          // 4 MB
    double*      PQ1w  = (double*)(ws + (190ull << 20));          // 4 MB
    double2*     MUIV1 = (double2*)(ws + (194ull << 20));         // 512 KB
    double2*     MUIV2 = (double2*)(ws + (210ull << 20));         // 512 KB

    prep_w_k<<<dim3(512), dim3(256), 0, stream>>>(W1, W2, W1p, W2p);

    for (int c = 0; c < 2; ++c) {
        const float* xc = x + (size_t)c * CM * DD;
        float* outc = out + (size_t)c * CM * DD;
        split_x_k<<<dim3(8192), dim3(256), 0, stream>>>(xc, Xp);
        gemm1_i8<<<dim3(2, CM / 32), dim3(256), 0, stream>>>(Xp, W1p, b1, Hn, PS1w, PQ1w);
        stats1_fin<<<dim3(CM / 256), dim3(256), 0, stream>>>(PS1w, PQ1w, MUIV1);
        lif1_k<<<dim3(CB * 8), dim3(64), 0, stream>>>(Hn, MUIV1, g1, be1, Sb);
        gemm2_i8<<<dim3(CM / 32), dim3(256), 0, stream>>>(Sb, W2p, b2, Yn, MUIV2);
        lif2_k<<<dim3(CB * 4), dim3(64), 0, stream>>>(Yn, MUIV2, g2, be2, xc, outc);
    }
}